// Round 3
// baseline (434.001 us; speedup 1.0000x reference)
//
#include <hip/hip_runtime.h>

// ---------------------------------------------------------------------------
// EncoderDecoderAttentionHead. All GEMMs as A[M,K] @ B[N,K]^T, bf16 MFMA.
// R3 GEMM: BK=32, 4-deep LDS ring, 1 barrier + counted vmcnt per K-tile,
// paired-row XOR swizzle (conflict-free at 64B rows), XCD+supertile block
// swizzle. Two shapes: BM=256 (e-GEMM) / BM=128 (rest), BN=256, 8 waves.
// ---------------------------------------------------------------------------

typedef __attribute__((ext_vector_type(8))) __bf16 bf16x8;
typedef __attribute__((ext_vector_type(4))) float f32x4;
typedef __attribute__((ext_vector_type(4))) unsigned short ushort4v;
typedef __attribute__((ext_vector_type(8))) unsigned short ushort8v;

#define S_DIM 4096
#define T_DIM 4096
#define D_DIM 2048

__device__ __forceinline__ unsigned short f2bf(float f) {
    unsigned int u = __float_as_uint(f);
    u += 0x7fffu + ((u >> 16) & 1u);
    return (unsigned short)(u >> 16);
}

__device__ __forceinline__ void block_sync() {
    __builtin_amdgcn_sched_barrier(0);
    __builtin_amdgcn_s_barrier();
    __builtin_amdgcn_sched_barrier(0);
}

#define GL(gptr, sptr)                                                        \
    __builtin_amdgcn_global_load_lds(                                         \
        (__attribute__((address_space(1))) void*)(void*)(gptr),               \
        (__attribute__((address_space(3))) void*)(sptr), 16, 0, 0)

// ---- f32 -> bf16 convert ---------------------------------------------------
__global__ __launch_bounds__(256)
void k_convert(const float* __restrict__ in, unsigned short* __restrict__ out, long n) {
    long i = ((long)blockIdx.x * blockDim.x + threadIdx.x) * 8;
    const long stride = (long)gridDim.x * blockDim.x * 8;
    for (; i < n; i += stride) {
        float4 a = *(const float4*)(in + i);
        float4 b = *(const float4*)(in + i + 4);
        ushort8v o;
        o[0] = f2bf(a.x); o[1] = f2bf(a.y); o[2] = f2bf(a.z); o[3] = f2bf(a.w);
        o[4] = f2bf(b.x); o[5] = f2bf(b.y); o[6] = f2bf(b.z); o[7] = f2bf(b.w);
        *(ushort8v*)(out + i) = o;
    }
}

// ---- transpose f32 [R][C] -> bf16 [C][R] -----------------------------------
__global__ __launch_bounds__(256)
void k_transpose(const float* __restrict__ in, unsigned short* __restrict__ out,
                 int R, int C) {
    __shared__ float tile[32][33];
    const int bx = blockIdx.x * 32;
    const int by = blockIdx.y * 32;
    const int tx = threadIdx.x;
    const int ty = threadIdx.y;
    #pragma unroll
    for (int i = 0; i < 32; i += 8)
        tile[ty + i][tx] = in[(long)(by + ty + i) * C + bx + tx];
    __syncthreads();
    #pragma unroll
    for (int i = 0; i < 32; i += 8)
        out[(long)(bx + ty + i) * R + by + tx] = f2bf(tile[tx][ty + i]);
}

// ---- ring-pipelined bf16 GEMM ----------------------------------------------
// Granule layout per tile (A: BM rows x 32k; B: 256 rows x 32k), 16B granules:
// granule (R, s) holds global (row = 2R+(c'&1), chunk c'>>1), c' = s ^ (R&7).
// ds_read (row rr, chunk c): byte = (rr>>1)*128 + (((c<<1)|(rr&1))^((rr>>1)&7))*16.
template<int BM, int OUT_BF16, int HAS_BIAS>
__global__ __launch_bounds__(512, 2)
void k_gemm(const unsigned short* __restrict__ A,
            const unsigned short* __restrict__ B,
            const float* __restrict__ bias,
            void* __restrict__ C,
            int M, int N, int K, float alpha) {
    constexpr int MFR    = BM / 32;        // m-frags per wave: 8 (BM=256) / 4
    constexpr int AGRAN  = BM * 4;         // A-tile granules
    constexpr int ALOADS = AGRAN / 512;    // A loads/thread/tile: 2 / 1
    constexpr int LDSA   = AGRAN * 16;     // A-tile bytes
    constexpr int BUF    = LDSA + 16384;   // + B tile (1024 granules)
    extern __shared__ __align__(16) char smem[];

    const int tid = threadIdx.x;
    const int l = tid & 63;
    const int w = tid >> 6;
    const int wr = w >> 2;                 // 0..1
    const int wc = w & 3;                  // 0..3

    // ---- XCD-chunked + 8x4 supertile block swizzle (nwg%8==0, gx%4==0) ----
    const int gx = gridDim.x, gy = gridDim.y;
    const int flat = blockIdx.y * gx + blockIdx.x;
    const int per = (gx * gy) >> 3;
    const int wid = (flat & 7) * per + (flat >> 3);
    const int sc = wid / (gy * 4);
    const int rm = wid - sc * gy * 4;
    const int by = rm >> 2;
    const int bx = sc * 4 + (rm & 3);

    const long brow = (long)by * BM;
    const long bcol = (long)bx * 256;
    const int NT = K >> 5;

    // ---- staging slots ----
    const unsigned short* gA[ALOADS];
    int ldA[ALOADS];
    #pragma unroll
    for (int j = 0; j < ALOADS; ++j) {
        const int q = (w * ALOADS + j) * 64 + l;
        const int R = q >> 3, s = q & 7, cp = s ^ (R & 7);
        gA[j] = A + (brow + 2 * R + (cp & 1)) * (long)K + (cp >> 1) * 8;
        ldA[j] = q * 16;
    }
    const unsigned short* gB[2];
    int ldB[2];
    #pragma unroll
    for (int j = 0; j < 2; ++j) {
        const int q = (w * 2 + j) * 64 + l;
        const int R = q >> 3, s = q & 7, cp = s ^ (R & 7);
        gB[j] = B + (bcol + 2 * R + (cp & 1)) * (long)K + (cp >> 1) * 8;
        ldB[j] = LDSA + q * 16;
    }

    // ---- ds_read bases (swizzled, lane-constant) ----
    const int sAB = (((((l >> 4) << 1) | (l & 1)) ^ ((l >> 1) & 7)) << 4);
    const int arB = (wr * (BM / 4) + ((l & 15) >> 1)) * 128 + sAB;
    const int brB = LDSA + (wc * 32 + ((l & 15) >> 1)) * 128 + sAB;

    f32x4 acc[MFR][4] = {};

    auto stage = [&](char* dst) {
        #pragma unroll
        for (int j = 0; j < ALOADS; ++j) { GL(gA[j], dst + ldA[j]); gA[j] += 32; }
        #pragma unroll
        for (int j = 0; j < 2; ++j)      { GL(gB[j], dst + ldB[j]); gB[j] += 32; }
    };

    // ---- prologue: stage tiles 0,1,2 into ring slots 0,1,2 ----
    {
        char* d = smem;
        #pragma unroll
        for (int tt = 0; tt < 3; ++tt) { stage(d); d += BUF; }
        if constexpr (BM == 256) asm volatile("s_waitcnt vmcnt(8)" ::: "memory");
        else                     asm volatile("s_waitcnt vmcnt(6)" ::: "memory");
        block_sync();
    }

    auto tile = [&](char* cur, char* stg, int t) {
        if (t + 3 < NT) stage(stg);
        bf16x8 bfr[4], afr[MFR];
        #pragma unroll
        for (int n = 0; n < 4; ++n)
            bfr[n] = *(const bf16x8*)(cur + brB + n * 1024);
        #pragma unroll
        for (int m = 0; m < MFR; ++m)
            afr[m] = *(const bf16x8*)(cur + arB + m * 1024);
        __builtin_amdgcn_s_setprio(1);
        #pragma unroll
        for (int m = 0; m < MFR; ++m)
            #pragma unroll
            for (int n = 0; n < 4; ++n)
                acc[m][n] = __builtin_amdgcn_mfma_f32_16x16x32_bf16(
                    afr[m], bfr[n], acc[m][n], 0, 0, 0);
        __builtin_amdgcn_s_setprio(0);
        asm volatile("s_waitcnt lgkmcnt(0)" ::: "memory");
        if (t + 3 < NT) {        // tiles t+2,t+3 in flight; t+1 landed
            if constexpr (BM == 256) asm volatile("s_waitcnt vmcnt(8)" ::: "memory");
            else                     asm volatile("s_waitcnt vmcnt(6)" ::: "memory");
        } else if (t + 2 < NT) { // only t+2 in flight
            if constexpr (BM == 256) asm volatile("s_waitcnt vmcnt(4)" ::: "memory");
            else                     asm volatile("s_waitcnt vmcnt(3)" ::: "memory");
        } else if (t + 1 < NT) {
            asm volatile("s_waitcnt vmcnt(0)" ::: "memory");
        }
        if (t + 1 < NT) block_sync();
    };

    char* b0 = smem;
    char* b1 = smem + BUF;
    char* b2 = smem + 2 * BUF;
    char* b3 = smem + 3 * BUF;
    for (int t = 0; t < NT; t += 4) {
        tile(b0, b3, t);
        tile(b1, b0, t + 1);
        tile(b2, b1, t + 2);
        tile(b3, b2, t + 3);
    }

    // ---- epilogue: C/D layout col = lane&15, row = (lane>>4)*4 + reg -------
    const long crow0 = brow + wr * (BM / 2) + (l >> 4) * 4;
    const long ccol0 = bcol + wc * 64 + (l & 15);
    #pragma unroll
    for (int n = 0; n < 4; ++n) {
        const long col = ccol0 + n * 16;
        const float bb = HAS_BIAS ? bias[col] : 0.0f;
        #pragma unroll
        for (int m = 0; m < MFR; ++m) {
            #pragma unroll
            for (int r = 0; r < 4; ++r) {
                const long row = crow0 + m * 16 + r;
                const float v = acc[m][n][r] * alpha + bb;
                if (OUT_BF16)
                    ((unsigned short*)C)[row * N + col] = f2bf(v);
                else
                    ((float*)C)[row * N + col] = v;
            }
        }
    }
}

// ---- row softmax: e [S][T] f32 -> a [S][T] bf16 -----------------------------
__global__ __launch_bounds__(256)
void k_softmax(const float* __restrict__ E, unsigned short* __restrict__ A, int T) {
    const long row = blockIdx.x;
    const float* er = E + row * (long)T;
    const int t = threadIdx.x;
    const int l = t & 63;
    const int w = t >> 6;

    float4 v[4];
    float m = -3.4e38f;
    #pragma unroll
    for (int j = 0; j < 4; ++j) {
        v[j] = *(const float4*)(er + j * 1024 + t * 4);
        m = fmaxf(m, fmaxf(fmaxf(v[j].x, v[j].y), fmaxf(v[j].z, v[j].w)));
    }
    #pragma unroll
    for (int o = 32; o > 0; o >>= 1) m = fmaxf(m, __shfl_xor(m, o));

    __shared__ float redm[4];
    __shared__ float reds[4];
    if (l == 0) redm[w] = m;
    __syncthreads();
    m = fmaxf(fmaxf(redm[0], redm[1]), fmaxf(redm[2], redm[3]));

    float s = 0.f;
    #pragma unroll
    for (int j = 0; j < 4; ++j) {
        v[j].x = __expf(v[j].x - m); s += v[j].x;
        v[j].y = __expf(v[j].y - m); s += v[j].y;
        v[j].z = __expf(v[j].z - m); s += v[j].z;
        v[j].w = __expf(v[j].w - m); s += v[j].w;
    }
    #pragma unroll
    for (int o = 32; o > 0; o >>= 1) s += __shfl_xor(s, o);
    if (l == 0) reds[w] = s;
    __syncthreads();
    s = reds[0] + reds[1] + reds[2] + reds[3];
    const float inv = 1.0f / s;

    unsigned short* ar = A + row * (long)T;
    #pragma unroll
    for (int j = 0; j < 4; ++j) {
        ushort4v o4;
        o4[0] = f2bf(v[j].x * inv);
        o4[1] = f2bf(v[j].y * inv);
        o4[2] = f2bf(v[j].z * inv);
        o4[3] = f2bf(v[j].w * inv);
        *(ushort4v*)(ar + j * 1024 + t * 4) = o4;
    }
}

// ---------------------------------------------------------------------------
extern "C" void kernel_launch(void* const* d_in, const int* in_sizes, int n_in,
                              void* d_out, int out_size, void* d_ws, size_t ws_size,
                              hipStream_t stream) {
    const float* x   = (const float*)d_in[0];   // [S][D]
    const float* enc = (const float*)d_in[1];   // [2][T][S]
    const float* Wq  = (const float*)d_in[2];   // [D][D]
    const float* bq  = (const float*)d_in[3];   // [D]
    float* out = (float*)d_out;                 // [S][D]
    char* ws = (char*)d_ws;

    unsigned short* xT    = (unsigned short*)(ws);                 // [D][S] 16MB
    unsigned short* xbf   = (unsigned short*)(ws + (16L << 20));   // [S][D] 16MB
    unsigned short* wqbf  = (unsigned short*)(ws + (32L << 20));   // [D][D]  8MB
    unsigned short* qbf   = (unsigned short*)(ws + (40L << 20));   // [S][D] 16MB
    unsigned short* kbf   = (unsigned short*)(ws + (56L << 20));   // [T][D] 16MB
    unsigned short* vT    = (unsigned short*)(ws + (72L << 20));   // [D][T] 16MB
    unsigned short* encbf = (unsigned short*)(ws + (88L << 20));   // [2][T][S] 64MB
    float*          e     = (float*)(ws + (88L << 20));            // [S][T] 64MB (reuse)
    unsigned short* abf   = (unsigned short*)(ws + (152L << 20));  // [S][T] 32MB

    k_convert<<<4096, 256, 0, stream>>>(x,   xbf,   (long)S_DIM * D_DIM);
    k_convert<<<4096, 256, 0, stream>>>(Wq,  wqbf,  (long)D_DIM * D_DIM);
    k_convert<<<4096, 256, 0, stream>>>(enc, encbf, 2L * T_DIM * S_DIM);
    k_transpose<<<dim3(D_DIM / 32, S_DIM / 32), dim3(32, 8), 0, stream>>>(x, xT, S_DIM, D_DIM);

    #define LAUNCH_G(BMV, OB, HB, Ap, Bp, biasp, Cp, M_, N_, K_, al)                       \
        do {                                                                               \
            constexpr int smemB = (BMV * 4 + 1024) * 16 * 4;                               \
            hipFuncSetAttribute((const void*)k_gemm<BMV, OB, HB>,                          \
                                hipFuncAttributeMaxDynamicSharedMemorySize, smemB);        \
            k_gemm<BMV, OB, HB><<<dim3((N_) / 256, (M_) / BMV), 512, smemB, stream>>>(     \
                Ap, Bp, biasp, Cp, M_, N_, K_, al);                                        \
        } while (0)

    // q = x @ Wq^T + bq           [S,D]   grid (8,32)
    LAUNCH_G(128, 1, 1, xbf, wqbf, bq, qbf, S_DIM, D_DIM, D_DIM, 1.0f);
    // k = enc0 @ xT^T             [T,D]   grid (8,32)
    LAUNCH_G(128, 1, 0, encbf, xT, nullptr, kbf, T_DIM, D_DIM, S_DIM, 1.0f);
    // vT = xT @ enc1^T            [D,T]   grid (16,16)
    LAUNCH_G(128, 1, 0, xT, encbf + (long)T_DIM * S_DIM, nullptr, vT, D_DIM, T_DIM, S_DIM, 1.0f);
    // e = q @ k^T / sqrt(D)       [S,T]   grid (16,16), fp32
    LAUNCH_G(256, 0, 0, qbf, kbf, nullptr, e, S_DIM, T_DIM, D_DIM, 0.022097086912079608f);
    // a = softmax(e)              [S,T] bf16
    k_softmax<<<S_DIM, 256, 0, stream>>>(e, abf, T_DIM);
    // z = a @ vT^T                [S,D]   grid (8,32), fp32 -> d_out
    LAUNCH_G(128, 0, 0, abf, vT, nullptr, out, S_DIM, D_DIM, T_DIM, 1.0f);
}

// Round 4
// 391.418 us; speedup vs baseline: 1.1088x; 1.1088x over previous
//
#include <hip/hip_runtime.h>

// ---------------------------------------------------------------------------
// EncoderDecoderAttentionHead. All GEMMs as A[M,K] @ B[N,K]^T, bf16 MFMA.
// R4: single-segment-per-K-tile GEMM with register loads staggered one
// segment ahead, ring-4 LDS (BK=32), counted vmcnt, paired-row XOR swizzle,
// setprio. kv fused into one M=8192 GEMM (enc[2TS] is contiguous), so the
// BM=256 config keeps a 256-block grid; q,z use BM=128 (grid 256).
// ---------------------------------------------------------------------------

typedef __attribute__((ext_vector_type(8))) __bf16 bf16x8;
typedef __attribute__((ext_vector_type(4))) float f32x4;
typedef __attribute__((ext_vector_type(4))) unsigned short ushort4v;
typedef __attribute__((ext_vector_type(8))) unsigned short ushort8v;

#define S_DIM 4096
#define T_DIM 4096
#define D_DIM 2048

__device__ __forceinline__ unsigned short f2bf(float f) {
    unsigned int u = __float_as_uint(f);
    u += 0x7fffu + ((u >> 16) & 1u);
    return (unsigned short)(u >> 16);
}

__device__ __forceinline__ void block_sync() {
    __builtin_amdgcn_sched_barrier(0);
    __builtin_amdgcn_s_barrier();
    __builtin_amdgcn_sched_barrier(0);
}

#define GL(gptr, sptr)                                                        \
    __builtin_amdgcn_global_load_lds(                                         \
        (__attribute__((address_space(1))) void*)(void*)(gptr),               \
        (__attribute__((address_space(3))) void*)(sptr), 16, 0, 0)

__device__ __forceinline__ f32x4 MFMA(bf16x8 a, bf16x8 b, f32x4 c) {
    return __builtin_amdgcn_mfma_f32_16x16x32_bf16(a, b, c, 0, 0, 0);
}

// ---- f32 -> bf16 convert ---------------------------------------------------
__global__ __launch_bounds__(256)
void k_convert(const float* __restrict__ in, unsigned short* __restrict__ out, long n) {
    long i = ((long)blockIdx.x * blockDim.x + threadIdx.x) * 8;
    const long stride = (long)gridDim.x * blockDim.x * 8;
    for (; i < n; i += stride) {
        float4 a = *(const float4*)(in + i);
        float4 b = *(const float4*)(in + i + 4);
        ushort8v o;
        o[0] = f2bf(a.x); o[1] = f2bf(a.y); o[2] = f2bf(a.z); o[3] = f2bf(a.w);
        o[4] = f2bf(b.x); o[5] = f2bf(b.y); o[6] = f2bf(b.z); o[7] = f2bf(b.w);
        *(ushort8v*)(out + i) = o;
    }
}

// ---- transpose f32 [R][C] -> bf16 [C][R] -----------------------------------
__global__ __launch_bounds__(256)
void k_transpose(const float* __restrict__ in, unsigned short* __restrict__ out,
                 int R, int C) {
    __shared__ float tile[32][33];
    const int bx = blockIdx.x * 32;
    const int by = blockIdx.y * 32;
    const int tx = threadIdx.x;
    const int ty = threadIdx.y;
    #pragma unroll
    for (int i = 0; i < 32; i += 8)
        tile[ty + i][tx] = in[(long)(by + ty + i) * C + bx + tx];
    __syncthreads();
    #pragma unroll
    for (int i = 0; i < 32; i += 8)
        out[(long)(bx + ty + i) * R + by + tx] = f2bf(tile[tx][ty + i]);
}

// ---- transpose bf16 [R][C] -> bf16 [C][R] ----------------------------------
__global__ __launch_bounds__(256)
void k_transpose_bf(const unsigned short* __restrict__ in,
                    unsigned short* __restrict__ out, int R, int C) {
    __shared__ unsigned short tile[32][33];
    const int bx = blockIdx.x * 32;
    const int by = blockIdx.y * 32;
    const int tx = threadIdx.x;
    const int ty = threadIdx.y;
    #pragma unroll
    for (int i = 0; i < 32; i += 8)
        tile[ty + i][tx] = in[(long)(by + ty + i) * C + bx + tx];
    __syncthreads();
    #pragma unroll
    for (int i = 0; i < 32; i += 8)
        out[(long)(bx + ty + i) * R + by + tx] = tile[tx][ty + i];
}

// ---- one pipeline segment (= one K-tile of 32) ------------------------------
// Consumes tile t from registers (au/bu[/a47 read here from cur]), prefetches
// tile t+1's fragments into (af/bf_) from nxt, stages tile t+3 into stg.
template<int MFR, bool DOSTG, bool DOREAD, int WVM, bool DOBAR, int LPTA>
__device__ __forceinline__ void seg_t(
    const unsigned short* (&gA)[2], const int (&ldA)[2],
    const unsigned short* (&gB)[2], const int (&ldB)[2],
    char* cur, char* nxt, char* stg, int arB, int brB,
    bf16x8 (&au)[4], bf16x8 (&bu)[4], bf16x8 (&af)[4], bf16x8 (&bf_)[4],
    f32x4 (&acc)[MFR][4])
{
    bf16x8 a47[4];
    if constexpr (MFR == 8) {
        #pragma unroll
        for (int j = 0; j < 4; ++j)
            a47[j] = *(const bf16x8*)(cur + arB + (4 + j) * 1024);
    }
    if constexpr (DOSTG) {
        #pragma unroll
        for (int j = 0; j < LPTA; ++j) { GL(gA[j], stg + ldA[j]); gA[j] += 32; }
        #pragma unroll
        for (int j = 0; j < 2; ++j)    { GL(gB[j], stg + ldB[j]); gB[j] += 32; }
    }
    if constexpr (DOREAD) {
        #pragma unroll
        for (int n = 0; n < 4; ++n)
            bf_[n] = *(const bf16x8*)(nxt + brB + n * 1024);
        #pragma unroll
        for (int m = 0; m < 4; ++m)
            af[m] = *(const bf16x8*)(nxt + arB + m * 1024);
    }
    // wait: au/bu (issued last segment) complete; newer reads stay in flight
    if constexpr (MFR == 8 && DOREAD)  asm volatile("s_waitcnt lgkmcnt(12)" ::: "memory");
    else if constexpr (MFR == 8)       asm volatile("s_waitcnt lgkmcnt(4)" ::: "memory");
    else if constexpr (DOREAD)         asm volatile("s_waitcnt lgkmcnt(8)" ::: "memory");
    else                               asm volatile("s_waitcnt lgkmcnt(0)" ::: "memory");
    __builtin_amdgcn_sched_barrier(0);
    __builtin_amdgcn_s_setprio(1);
    #pragma unroll
    for (int m = 0; m < 4; ++m)
        #pragma unroll
        for (int n = 0; n < 4; ++n)
            acc[m][n] = MFMA(au[m], bu[n], acc[m][n]);
    if constexpr (MFR == 8) {
        if constexpr (DOREAD) asm volatile("s_waitcnt lgkmcnt(8)" ::: "memory");
        else                  asm volatile("s_waitcnt lgkmcnt(0)" ::: "memory");
        __builtin_amdgcn_sched_barrier(0);
        #pragma unroll
        for (int j = 0; j < 4; ++j)
            #pragma unroll
            for (int n = 0; n < 4; ++n)
                acc[4 + j][n] = MFMA(a47[j], bu[n], acc[4 + j][n]);
    }
    __builtin_amdgcn_s_setprio(0);
    if constexpr (WVM == 4)      asm volatile("s_waitcnt vmcnt(4)" ::: "memory");
    else if constexpr (WVM == 3) asm volatile("s_waitcnt vmcnt(3)" ::: "memory");
    else if constexpr (WVM == 0) asm volatile("s_waitcnt vmcnt(0)" ::: "memory");
    if constexpr (DOBAR) block_sync();
}

// ---- pipelined bf16 GEMM, C[M,N] = alpha*A[M,K]@B[N,K]^T (+bias[col]) ------
// BM = MFR*32, BN = 256, BK = 32, 8 waves (2 x 4), wave tile (MFR*16) x 64.
// LDS granule (R,s): holds global (row = 2R+(c'&1), chunk8 = c'>>1), c'=s^(R&7).
template<int MFR, int OUT_BF16, int HAS_BIAS>
__global__ __launch_bounds__(512, 2)
void k_gemm(const unsigned short* __restrict__ A,
            const unsigned short* __restrict__ B,
            const float* __restrict__ bias,
            void* __restrict__ C,
            int M, int N, int K, float alpha) {
    constexpr int BM    = MFR * 32;
    constexpr int AGRAN = BM * 4;            // 16B granules in A tile
    constexpr int LPTA  = AGRAN / 512;       // A loads/thread/tile (2 or 1)
    constexpr int LDSA  = AGRAN * 16;        // A tile bytes
    constexpr int SLOT  = LDSA + 16384;      // + B tile (1024 granules)
    constexpr int LPT   = LPTA + 2;          // loads/thread/tile total
    extern __shared__ __align__(16) char smem[];

    const int tid = threadIdx.x;
    const int l = tid & 63;
    const int w = tid >> 6;
    const int wr = w >> 2;                   // 0..1
    const int wc = w & 3;                    // 0..3

    // XCD-chunked + 4-col supertile block swizzle (grid always 256, gx%4==0)
    const int gx = gridDim.x, gy = gridDim.y;
    const int flat = blockIdx.y * gx + blockIdx.x;
    const int per = (gx * gy) >> 3;
    const int wid = (flat & 7) * per + (flat >> 3);
    const int sc = wid / (gy * 4);
    const int rm = wid - sc * gy * 4;
    const int by = rm >> 2;
    const int bx = sc * 4 + (rm & 3);

    const long brow = (long)by * BM;
    const long bcol = (long)bx * 256;
    const int NT = K >> 5;

    // staging slots
    const unsigned short* gA[2];
    int ldA[2];
    #pragma unroll
    for (int j = 0; j < LPTA; ++j) {
        const int q = (w * LPTA + j) * 64 + l;
        const int R = q >> 3, s = q & 7, cp = s ^ (R & 7);
        gA[j] = A + (brow + 2 * R + (cp & 1)) * (long)K + (cp >> 1) * 8;
        ldA[j] = q * 16;
    }
    const unsigned short* gB[2];
    int ldB[2];
    #pragma unroll
    for (int j = 0; j < 2; ++j) {
        const int q = (w * 2 + j) * 64 + l;
        const int R = q >> 3, s = q & 7, cp = s ^ (R & 7);
        gB[j] = B + (bcol + 2 * R + (cp & 1)) * (long)K + (cp >> 1) * 8;
        ldB[j] = LDSA + q * 16;
    }

    // ds_read bases (swizzled, lane-constant): fragment row rr=(l&15), chunk c=(l>>4)
    const int sAB = ((((l >> 4) << 1) | (l & 1)) ^ ((l & 15) >> 1)) << 4;
    const int arB = (wr * (MFR * 8) + ((l & 15) >> 1)) * 128 + sAB;
    const int brB = LDSA + (wc * 32 + ((l & 15) >> 1)) * 128 + sAB;

    char* P0 = smem;
    char* P1 = smem + SLOT;
    char* P2 = smem + 2 * SLOT;
    char* P3 = smem + 3 * SLOT;

    f32x4 acc[MFR][4] = {};
    bf16x8 aE[4], bE[4], aO[4], bO[4];

    // prologue: stage tiles 0,1,2; confirm 0,1; preload tile-0 fragments
    {
        auto stage = [&](char* dst) {
            #pragma unroll
            for (int j = 0; j < LPTA; ++j) { GL(gA[j], dst + ldA[j]); gA[j] += 32; }
            #pragma unroll
            for (int j = 0; j < 2; ++j)    { GL(gB[j], dst + ldB[j]); gB[j] += 32; }
        };
        stage(P0); stage(P1); stage(P2);
        if constexpr (MFR == 8) asm volatile("s_waitcnt vmcnt(4)" ::: "memory");
        else                    asm volatile("s_waitcnt vmcnt(3)" ::: "memory");
        block_sync();
        #pragma unroll
        for (int n = 0; n < 4; ++n) bE[n] = *(const bf16x8*)(P0 + brB + n * 1024);
        #pragma unroll
        for (int m = 0; m < 4; ++m) aE[m] = *(const bf16x8*)(P0 + arB + m * 1024);
    }

    constexpr int WVM = (MFR == 8) ? 4 : 3;
    // main loop: pairs of tiles, full stage + prefetch; exits with t == NT-4
    for (int t = 0; t + 6 <= NT; t += 2) {
        seg_t<MFR, true, true, WVM, true, LPTA>(gA, ldA, gB, ldB, P0, P1, P3,
                                                arB, brB, aE, bE, aO, bO, acc);
        seg_t<MFR, true, true, WVM, true, LPTA>(gA, ldA, gB, ldB, P1, P2, P0,
                                                arB, brB, aO, bO, aE, bE, acc);
        char* tp = P0; P0 = P2; P2 = tp;
        tp = P1; P1 = P3; P3 = tp;
    }
    // tail: tiles NT-4 .. NT-1
    seg_t<MFR, true,  true, WVM, true, LPTA>(gA, ldA, gB, ldB, P0, P1, P3,
                                             arB, brB, aE, bE, aO, bO, acc);
    seg_t<MFR, false, true, 0,   true, LPTA>(gA, ldA, gB, ldB, P1, P2, nullptr,
                                             arB, brB, aO, bO, aE, bE, acc);
    seg_t<MFR, false, true, -1,  true, LPTA>(gA, ldA, gB, ldB, P2, P3, nullptr,
                                             arB, brB, aE, bE, aO, bO, acc);
    seg_t<MFR, false, false, -1, false, LPTA>(gA, ldA, gB, ldB, P3, nullptr, nullptr,
                                              arB, brB, aO, bO, aE, bE, acc);

    // epilogue: C/D layout col = lane&15, row = (lane>>4)*4 + reg
    const long crow0 = brow + wr * (MFR * 16) + (l >> 4) * 4;
    const long ccol0 = bcol + wc * 64 + (l & 15);
    #pragma unroll
    for (int n = 0; n < 4; ++n) {
        const long col = ccol0 + n * 16;
        const float bb = HAS_BIAS ? bias[col] : 0.0f;
        #pragma unroll
        for (int m = 0; m < MFR; ++m) {
            #pragma unroll
            for (int r = 0; r < 4; ++r) {
                const long row = crow0 + m * 16 + r;
                const float v = acc[m][n][r] * alpha + bb;
                if (OUT_BF16)
                    ((unsigned short*)C)[row * N + col] = f2bf(v);
                else
                    ((float*)C)[row * N + col] = v;
            }
        }
    }
}

// ---- row softmax: e [S][T] f32 -> a [S][T] bf16 -----------------------------
__global__ __launch_bounds__(256)
void k_softmax(const float* __restrict__ E, unsigned short* __restrict__ A, int T) {
    const long row = blockIdx.x;
    const float* er = E + row * (long)T;
    const int t = threadIdx.x;
    const int l = t & 63;
    const int w = t >> 6;

    float4 v[4];
    float m = -3.4e38f;
    #pragma unroll
    for (int j = 0; j < 4; ++j) {
        v[j] = *(const float4*)(er + j * 1024 + t * 4);
        m = fmaxf(m, fmaxf(fmaxf(v[j].x, v[j].y), fmaxf(v[j].z, v[j].w)));
    }
    #pragma unroll
    for (int o = 32; o > 0; o >>= 1) m = fmaxf(m, __shfl_xor(m, o));

    __shared__ float redm[4];
    __shared__ float reds[4];
    if (l == 0) redm[w] = m;
    __syncthreads();
    m = fmaxf(fmaxf(redm[0], redm[1]), fmaxf(redm[2], redm[3]));

    float s = 0.f;
    #pragma unroll
    for (int j = 0; j < 4; ++j) {
        v[j].x = __expf(v[j].x - m); s += v[j].x;
        v[j].y = __expf(v[j].y - m); s += v[j].y;
        v[j].z = __expf(v[j].z - m); s += v[j].z;
        v[j].w = __expf(v[j].w - m); s += v[j].w;
    }
    #pragma unroll
    for (int o = 32; o > 0; o >>= 1) s += __shfl_xor(s, o);
    if (l == 0) reds[w] = s;
    __syncthreads();
    s = reds[0] + reds[1] + reds[2] + reds[3];
    const float inv = 1.0f / s;

    unsigned short* ar = A + row * (long)T;
    #pragma unroll
    for (int j = 0; j < 4; ++j) {
        ushort4v o4;
        o4[0] = f2bf(v[j].x * inv);
        o4[1] = f2bf(v[j].y * inv);
        o4[2] = f2bf(v[j].z * inv);
        o4[3] = f2bf(v[j].w * inv);
        *(ushort4v*)(ar + j * 1024 + t * 4) = o4;
    }
}

// ---------------------------------------------------------------------------
extern "C" void kernel_launch(void* const* d_in, const int* in_sizes, int n_in,
                              void* d_out, int out_size, void* d_ws, size_t ws_size,
                              hipStream_t stream) {
    const float* x   = (const float*)d_in[0];   // [S][D]
    const float* enc = (const float*)d_in[1];   // [2][T][S]
    const float* Wq  = (const float*)d_in[2];   // [D][D]
    const float* bq  = (const float*)d_in[3];   // [D]
    float* out = (float*)d_out;                 // [S][D]
    char* ws = (char*)d_ws;

    // abf overlaps xT/xbf (dead before softmax). Total footprint 168 MB.
    unsigned short* abf   = (unsigned short*)(ws);                 // [S][T]   32MB (late)
    unsigned short* xT    = (unsigned short*)(ws);                 // [D][S]   16MB (early)
    unsigned short* xbf   = (unsigned short*)(ws + (16L << 20));   // [S][D]   16MB (early)
    unsigned short* wqbf  = (unsigned short*)(ws + (32L << 20));   // [D][D]    8MB
    unsigned short* qbf   = (unsigned short*)(ws + (40L << 20));   // [S][D]   16MB
    unsigned short* kv    = (unsigned short*)(ws + (56L << 20));   // [2T][D]  32MB
    unsigned short* vT    = (unsigned short*)(ws + (88L << 20));   // [D][T]   16MB
    unsigned short* encbf = (unsigned short*)(ws + (104L << 20));  // [2][T][S] 64MB (early)
    float*          e     = (float*)(ws + (104L << 20));           // [S][T]   64MB (reuse)

    k_convert<<<4096, 256, 0, stream>>>(x,   xbf,   (long)S_DIM * D_DIM);
    k_convert<<<4096, 256, 0, stream>>>(Wq,  wqbf,  (long)D_DIM * D_DIM);
    k_convert<<<4096, 256, 0, stream>>>(enc, encbf, 2L * T_DIM * S_DIM);
    k_transpose<<<dim3(D_DIM / 32, S_DIM / 32), dim3(32, 8), 0, stream>>>(x, xT, S_DIM, D_DIM);

    #define LAUNCH_G(MFRV, OB, HB, Ap, Bp, biasp, Cp, M_, N_, K_, al)                      \
        do {                                                                               \
            constexpr int smemB = ((MFRV * 32 * 4) * 16 + 16384) * 4;                      \
            hipFuncSetAttribute((const void*)k_gemm<MFRV, OB, HB>,                         \
                                hipFuncAttributeMaxDynamicSharedMemorySize, smemB);        \
            k_gemm<MFRV, OB, HB><<<dim3((N_) / 256, (M_) / (MFRV * 32)), 512, smemB,       \
                                   stream>>>(Ap, Bp, biasp, Cp, M_, N_, K_, al);           \
        } while (0)

    // q = x @ Wq^T + bq            [4096,2048]  grid (8,32)
    LAUNCH_G(4, 1, 1, xbf, wqbf, bq, qbf, S_DIM, D_DIM, D_DIM, 1.0f);
    // kv = enc @ xT^T (k rows 0..T-1, v rows T..2T-1)  [8192,2048]  grid (8,32)
    LAUNCH_G(8, 1, 0, encbf, xT, nullptr, kv, 2 * T_DIM, D_DIM, S_DIM, 1.0f);
    // vT = transpose(v)            [2048,4096]
    k_transpose_bf<<<dim3(D_DIM / 32, T_DIM / 32), dim3(32, 8), 0, stream>>>(
        kv + (long)T_DIM * D_DIM, vT, T_DIM, D_DIM);
    // e = q @ k^T / sqrt(D)        [4096,4096]  grid (16,16), fp32
    LAUNCH_G(8, 0, 0, qbf, kv, nullptr, e, S_DIM, T_DIM, D_DIM, 0.022097086912079608f);
    // a = softmax(e)               [S,T] bf16
    k_softmax<<<S_DIM, 256, 0, stream>>>(e, abf, T_DIM);
    // z = a @ vT^T                 [4096,2048]  grid (8,32), fp32 -> d_out
    LAUNCH_G(4, 0, 0, abf, vT, nullptr, out, S_DIM, D_DIM, T_DIM, 1.0f);
}